// Round 1
// baseline (570.152 us; speedup 1.0000x reference)
//
#include <hip/hip_runtime.h>

#define NB 8192
#define NH 50
#define ND 64

__device__ __forceinline__ float wsum(float v) {
#pragma unroll
    for (int o = 32; o > 0; o >>= 1) v += __shfl_xor(v, o, 64);
    return v;
}
__device__ __forceinline__ float wmax(float v) {
#pragma unroll
    for (int o = 32; o > 0; o >>= 1) v = fmaxf(v, __shfl_xor(v, o, 64));
    return v;
}

__global__ void zero_tail_kernel(float* __restrict__ out) {
    out[4 * NB] = 0.0f;
    out[4 * NB + 1] = 0.0f;
}

__global__ __launch_bounds__(256, 2) void fwd_kernel(
    const int* __restrict__ user1, const int* __restrict__ item1,
    const int* __restrict__ user2, const int* __restrict__ item2,
    const int* __restrict__ u_his, const int* __restrict__ u_pos, const int* __restrict__ u_mask,
    const int* __restrict__ i_his, const int* __restrict__ i_pos, const int* __restrict__ i_mask,
    const float* __restrict__ user1_emb, const float* __restrict__ item1_emb,
    const float* __restrict__ user1_bias, const float* __restrict__ item1_bias,
    const float* __restrict__ u_pos_emb,
    const float* __restrict__ user2_emb, const float* __restrict__ item2_emb,
    const float* __restrict__ user2_bias, const float* __restrict__ item2_bias,
    const float* __restrict__ i_pos_emb,
    const float* __restrict__ attn_u_W, const float* __restrict__ attn_u_b,
    const float* __restrict__ attn_i_W, const float* __restrict__ attn_i_b,
    float* __restrict__ out)
{
    const int wave = threadIdx.x >> 6;
    const int b = blockIdx.x * 4 + wave;
    const int d = threadIdx.x & 63;

    // --- per-sample scalar indices (wave-uniform -> scalar loads) ---
    const int iu1 = user1[b], ii1 = item1[b], iu2 = user2[b], ii2 = item2[b];

    // --- per-sample embedding rows (lane d holds element d) ---
    const float u1s = user1_emb[(long)iu1 * ND + d];
    const float i1s = item1_emb[(long)ii1 * ND + d];
    const float u1r = user2_emb[(long)iu1 * ND + d];
    const float i1r = item2_emb[(long)ii1 * ND + d];
    const float u2s = user2_emb[(long)iu2 * ND + d];
    const float i2s = item2_emb[(long)ii2 * ND + d];
    const float u2r = user1_emb[(long)iu2 * ND + d];
    const float i2r = item1_emb[(long)ii2 * ND + d];

    // --- attention weight vectors: W[0:64] hits the query (data), W[64:128] the key ---
    const float Wqu = attn_u_W[d], Wku = attn_u_W[ND + d];
    const float Wqi = attn_i_W[d], Wki = attn_i_W[ND + d];
    const float bu = attn_u_b[0], bi = attn_i_b[0];

    // query-side score constants (uniform after reduce)
    const float cq_us = wsum(i1s * Wqu);  // u_ds query = i1s
    const float cq_ur = wsum(i1r * Wqu);  // u_dr query = i1r
    const float cq_ir = wsum(u1r * Wqi);  // i_dr query = u1r
    const float cq_is = wsum(u1s * Wqi);  // i_ds query = u1s

    const bool valid = (d < NH);

    // ================= U-history attention (keys shared by u_ds and u_dr) =================
    float key_u[NH];
    float su_lane = 0.0f;   // lane h holds raw key·Wk score for history slot h
    float reg_u = 0.0f;     // per-lane partial of sum(u_hiss^2)
#pragma unroll
    for (int h = 0; h < NH; ++h) {
        const int ih = u_his[b * NH + h];
        const int ip = u_pos[b * NH + h];
        const float m = (u_mask[b * NH + h] != 0) ? 1.0f : 0.0f;
        const float ku = item1_emb[(long)ih * ND + d];
        const float pu = u_pos_emb[ip * ND + d];
        const float k = (ku + pu) * m;   // u_hiss + u_poss
        key_u[h] = k;
        reg_u += ku * ku * m;            // u_hiss^2 (mask in {0,1})
        const float s = wsum(k * Wku);
        if (d == h) su_lane = s;
    }
    // lane-parallel tanh + softmax over lanes 0..49 (masked slots DO join the softmax)
    float o_us = 0.0f, o_ur = 0.0f;
    {
        const float s_us = tanhf(cq_us + su_lane + bu);
        const float s_ur = tanhf(cq_ur + su_lane + bu);
        const float m_us = wmax(valid ? s_us : -1e30f);
        const float m_ur = wmax(valid ? s_ur : -1e30f);
        const float e_us = valid ? __expf(s_us - m_us) : 0.0f;
        const float e_ur = valid ? __expf(s_ur - m_ur) : 0.0f;
        const float w_us = e_us / wsum(e_us);
        const float w_ur = e_ur / wsum(e_ur);
#pragma unroll
        for (int h = 0; h < NH; ++h) {
            o_us += __shfl(w_us, h, 64) * key_u[h];
            o_ur += __shfl(w_ur, h, 64) * key_u[h];
        }
    }

    // ================= I-history attention (keys shared by i_dr and i_ds) =================
    float key_i[NH];
    float si_lane = 0.0f;
    float reg_i = 0.0f;     // partial of sum(i_hiss^2) = (user2_emb[i_his]*mi)^2
#pragma unroll
    for (int h = 0; h < NH; ++h) {
        const int ih = i_his[b * NH + h];
        const int ip = i_pos[b * NH + h];
        const float m = (i_mask[b * NH + h] != 0) ? 1.0f : 0.0f;
        const float ki = user2_emb[(long)ih * ND + d];
        const float pi = i_pos_emb[ip * ND + d];
        const float k = (ki + pi) * m;
        key_i[h] = k;
        reg_i += ki * ki * m;
        const float s = wsum(k * Wki);
        if (d == h) si_lane = s;
    }
    float o_ir = 0.0f, o_is = 0.0f;
    {
        const float s_ir = tanhf(cq_ir + si_lane + bi);
        const float s_is = tanhf(cq_is + si_lane + bi);
        const float m_ir = wmax(valid ? s_ir : -1e30f);
        const float m_is = wmax(valid ? s_is : -1e30f);
        const float e_ir = valid ? __expf(s_ir - m_ir) : 0.0f;
        const float e_is = valid ? __expf(s_is - m_is) : 0.0f;
        const float w_ir = e_ir / wsum(e_ir);
        const float w_is = e_is / wsum(e_is);
#pragma unroll
        for (int h = 0; h < NH; ++h) {
            o_ir += __shfl(w_ir, h, 64) * key_i[h];
            o_is += __shfl(w_is, h, 64) * key_i[h];
        }
    }

    // ================= logits + reg losses =================
    const float l_us = wsum((o_us + i1s) * u1s);
    const float l_ir = wsum((o_ir + i1r) * u1r);
    const float l_ur = wsum((o_ur + i2r) * u2r);
    const float l_is = wsum((o_is + i2s) * u2s);
    const float r1 = wsum(u1s * u1s + i1s * i1s + reg_u);
    const float r2 = wsum(u2s * u2s + i2s * i2s + reg_i);

    if (d == 0) {
        out[b]          = user1_bias[iu1] + item1_bias[ii1] + l_us;
        out[NB + b]     = user2_bias[iu1] + item2_bias[ii1] + l_ir;
        out[2 * NB + b] = user1_bias[iu2] + item1_bias[ii2] + l_ur;
        out[3 * NB + b] = user2_bias[iu2] + item2_bias[ii2] + l_is;
        atomicAdd(&out[4 * NB],     r1);
        atomicAdd(&out[4 * NB + 1], r2);
    }
}

extern "C" void kernel_launch(void* const* d_in, const int* in_sizes, int n_in,
                              void* d_out, int out_size, void* d_ws, size_t ws_size,
                              hipStream_t stream) {
    const int* user1 = (const int*)d_in[0];
    const int* item1 = (const int*)d_in[1];
    const int* user2 = (const int*)d_in[2];
    const int* item2 = (const int*)d_in[3];
    const int* u_his = (const int*)d_in[4];
    const int* u_pos = (const int*)d_in[5];
    const int* u_msk = (const int*)d_in[6];
    const int* i_his = (const int*)d_in[7];
    const int* i_pos = (const int*)d_in[8];
    const int* i_msk = (const int*)d_in[9];
    const float* user1_emb  = (const float*)d_in[10];
    const float* item1_emb  = (const float*)d_in[11];
    const float* user1_bias = (const float*)d_in[12];
    const float* item1_bias = (const float*)d_in[13];
    const float* u_pos_emb  = (const float*)d_in[14];
    const float* user2_emb  = (const float*)d_in[15];
    const float* item2_emb  = (const float*)d_in[16];
    const float* user2_bias = (const float*)d_in[17];
    const float* item2_bias = (const float*)d_in[18];
    const float* i_pos_emb  = (const float*)d_in[19];
    const float* attn_u_W = (const float*)d_in[20];
    const float* attn_u_b = (const float*)d_in[21];
    const float* attn_i_W = (const float*)d_in[22];
    const float* attn_i_b = (const float*)d_in[23];
    float* out = (float*)d_out;

    zero_tail_kernel<<<1, 1, 0, stream>>>(out);
    fwd_kernel<<<NB / 4, 256, 0, stream>>>(
        user1, item1, user2, item2,
        u_his, u_pos, u_msk, i_his, i_pos, i_msk,
        user1_emb, item1_emb, user1_bias, item1_bias, u_pos_emb,
        user2_emb, item2_emb, user2_bias, item2_bias, i_pos_emb,
        attn_u_W, attn_u_b, attn_i_W, attn_i_b,
        out);
}

// Round 2
// 355.190 us; speedup vs baseline: 1.6052x; 1.6052x over previous
//
#include <hip/hip_runtime.h>

#define NB 8192
#define NH 50
#define ND 64

__device__ __forceinline__ float wsum(float v) {
#pragma unroll
    for (int o = 32; o > 0; o >>= 1) v += __shfl_xor(v, o, 64);
    return v;
}

// tanh via single exp + hw rcp; |err| ~1e-7 relative, plenty for the threshold
__device__ __forceinline__ float tanh_fast(float x) {
    const float e = __expf(2.0f * x);
    return (e - 1.0f) * __builtin_amdgcn_rcpf(e + 1.0f);
}

__global__ void zero_tail_kernel(float* __restrict__ out) {
    out[4 * NB] = 0.0f;
    out[4 * NB + 1] = 0.0f;
}

__global__ __launch_bounds__(256, 4) void fwd_kernel(
    const int* __restrict__ user1, const int* __restrict__ item1,
    const int* __restrict__ user2, const int* __restrict__ item2,
    const int* __restrict__ u_his, const int* __restrict__ u_pos, const int* __restrict__ u_mask,
    const int* __restrict__ i_his, const int* __restrict__ i_pos, const int* __restrict__ i_mask,
    const float* __restrict__ user1_emb, const float* __restrict__ item1_emb,
    const float* __restrict__ user1_bias, const float* __restrict__ item1_bias,
    const float* __restrict__ u_pos_emb,
    const float* __restrict__ user2_emb, const float* __restrict__ item2_emb,
    const float* __restrict__ user2_bias, const float* __restrict__ item2_bias,
    const float* __restrict__ i_pos_emb,
    const float* __restrict__ attn_u_W, const float* __restrict__ attn_u_b,
    const float* __restrict__ attn_i_W, const float* __restrict__ attn_i_b,
    float* __restrict__ out)
{
    const int wave = threadIdx.x >> 6;
    const int b = blockIdx.x * 4 + wave;
    const int d = threadIdx.x & 63;

    const int iu1 = user1[b], ii1 = item1[b], iu2 = user2[b], ii2 = item2[b];

    // per-sample embedding rows (lane d holds element d)
    const float u1s = user1_emb[(long)iu1 * ND + d];
    const float i1s = item1_emb[(long)ii1 * ND + d];
    const float u1r = user2_emb[(long)iu1 * ND + d];
    const float i1r = item2_emb[(long)ii1 * ND + d];
    const float u2s = user2_emb[(long)iu2 * ND + d];
    const float i2s = item2_emb[(long)ii2 * ND + d];
    const float u2r = user1_emb[(long)iu2 * ND + d];
    const float i2r = item1_emb[(long)ii2 * ND + d];

    // attention weights: W[0:64] -> query (data), W[64:128] -> key
    const float Wku = attn_u_W[ND + d];
    const float Wki = attn_i_W[ND + d];
    const float bu = attn_u_b[0], bi = attn_i_b[0];

    // query-side score constants (wave-uniform after reduce)
    const float cq_us = wsum(i1s * attn_u_W[d]) + bu;  // u_ds query = i1s
    const float cq_ur = wsum(i1r * attn_u_W[d]) + bu;  // u_dr query = i1r
    const float cq_ir = wsum(u1r * attn_i_W[d]) + bi;  // i_dr query = u1r
    const float cq_is = wsum(u1s * attn_i_W[d]) + bi;  // i_ds query = u1s

    // ---- lane-parallel index/pos/mask loads (lane h holds slot h) ----
    int uh_v = 0, up_v = 0, ih_v = 0, ip_v = 0;
    float um_v = 0.0f, im_v = 0.0f;
    if (d < NH) {
        uh_v = u_his[b * NH + d];
        up_v = u_pos[b * NH + d];
        um_v = (u_mask[b * NH + d] != 0) ? 1.0f : 0.0f;
        ih_v = i_his[b * NH + d];
        ip_v = i_pos[b * NH + d];
        im_v = (i_mask[b * NH + d] != 0) ? 1.0f : 0.0f;
    }

    // ============ U-history: streaming softmax (tanh-bounded => no max shift) ============
    float o_us = 0.0f, o_ur = 0.0f, den_us = 0.0f, den_ur = 0.0f, reg_u = 0.0f;
#pragma unroll
    for (int h = 0; h < NH; ++h) {
        const int ih = __shfl(uh_v, h, 64);
        const int ip = __shfl(up_v, h, 64);
        const float m = __shfl(um_v, h, 64);
        const float ku = item1_emb[(long)ih * ND + d];
        const float pu = u_pos_emb[ip * ND + d];
        const float k = (ku + pu) * m;            // u_hiss + u_poss (masked)
        reg_u += ku * ku * m;                     // sum(u_hiss^2)
        const float s = wsum(k * Wku);            // broadcast key score
        const float e_us = __expf(tanh_fast(cq_us + s));
        const float e_ur = __expf(tanh_fast(cq_ur + s));
        o_us += e_us * k;  den_us += e_us;
        o_ur += e_ur * k;  den_ur += e_ur;
    }
    o_us *= __builtin_amdgcn_rcpf(den_us);
    o_ur *= __builtin_amdgcn_rcpf(den_ur);

    // ============ I-history ============
    float o_ir = 0.0f, o_is = 0.0f, den_ir = 0.0f, den_is = 0.0f, reg_i = 0.0f;
#pragma unroll
    for (int h = 0; h < NH; ++h) {
        const int ih = __shfl(ih_v, h, 64);
        const int ip = __shfl(ip_v, h, 64);
        const float m = __shfl(im_v, h, 64);
        const float ki = user2_emb[(long)ih * ND + d];
        const float pi = i_pos_emb[ip * ND + d];
        const float k = (ki + pi) * m;
        reg_i += ki * ki * m;                     // sum(i_hiss^2)
        const float s = wsum(k * Wki);
        const float e_ir = __expf(tanh_fast(cq_ir + s));
        const float e_is = __expf(tanh_fast(cq_is + s));
        o_ir += e_ir * k;  den_ir += e_ir;
        o_is += e_is * k;  den_is += e_is;
    }
    o_ir *= __builtin_amdgcn_rcpf(den_ir);
    o_is *= __builtin_amdgcn_rcpf(den_is);

    // ============ logits + reg losses ============
    const float l_us = wsum((o_us + i1s) * u1s);
    const float l_ir = wsum((o_ir + i1r) * u1r);
    const float l_ur = wsum((o_ur + i2r) * u2r);
    const float l_is = wsum((o_is + i2s) * u2s);
    const float r1 = wsum(u1s * u1s + i1s * i1s + reg_u);
    const float r2 = wsum(u2s * u2s + i2s * i2s + reg_i);

    __shared__ float red[8];
    if (d == 0) {
        out[b]          = user1_bias[iu1] + item1_bias[ii1] + l_us;
        out[NB + b]     = user2_bias[iu1] + item2_bias[ii1] + l_ir;
        out[2 * NB + b] = user1_bias[iu2] + item1_bias[ii2] + l_ur;
        out[3 * NB + b] = user2_bias[iu2] + item2_bias[ii2] + l_is;
        red[wave] = r1;
        red[4 + wave] = r2;
    }
    __syncthreads();
    if (threadIdx.x == 0) {
        atomicAdd(&out[4 * NB],     red[0] + red[1] + red[2] + red[3]);
        atomicAdd(&out[4 * NB + 1], red[4] + red[5] + red[6] + red[7]);
    }
}

extern "C" void kernel_launch(void* const* d_in, const int* in_sizes, int n_in,
                              void* d_out, int out_size, void* d_ws, size_t ws_size,
                              hipStream_t stream) {
    const int* user1 = (const int*)d_in[0];
    const int* item1 = (const int*)d_in[1];
    const int* user2 = (const int*)d_in[2];
    const int* item2 = (const int*)d_in[3];
    const int* u_his = (const int*)d_in[4];
    const int* u_pos = (const int*)d_in[5];
    const int* u_msk = (const int*)d_in[6];
    const int* i_his = (const int*)d_in[7];
    const int* i_pos = (const int*)d_in[8];
    const int* i_msk = (const int*)d_in[9];
    const float* user1_emb  = (const float*)d_in[10];
    const float* item1_emb  = (const float*)d_in[11];
    const float* user1_bias = (const float*)d_in[12];
    const float* item1_bias = (const float*)d_in[13];
    const float* u_pos_emb  = (const float*)d_in[14];
    const float* user2_emb  = (const float*)d_in[15];
    const float* item2_emb  = (const float*)d_in[16];
    const float* user2_bias = (const float*)d_in[17];
    const float* item2_bias = (const float*)d_in[18];
    const float* i_pos_emb  = (const float*)d_in[19];
    const float* attn_u_W = (const float*)d_in[20];
    const float* attn_u_b = (const float*)d_in[21];
    const float* attn_i_W = (const float*)d_in[22];
    const float* attn_i_b = (const float*)d_in[23];
    float* out = (float*)d_out;

    zero_tail_kernel<<<1, 1, 0, stream>>>(out);
    fwd_kernel<<<NB / 4, 256, 0, stream>>>(
        user1, item1, user2, item2,
        u_his, u_pos, u_msk, i_his, i_pos, i_msk,
        user1_emb, item1_emb, user1_bias, item1_bias, u_pos_emb,
        user2_emb, item2_emb, user2_bias, item2_bias, i_pos_emb,
        attn_u_W, attn_u_b, attn_i_W, attn_i_b,
        out);
}

// Round 3
// 264.236 us; speedup vs baseline: 2.1577x; 1.3442x over previous
//
#include <hip/hip_runtime.h>

#define NB 8192
#define NH 50
#define ND 64

__device__ __forceinline__ float wsum(float v) {
#pragma unroll
    for (int o = 32; o > 0; o >>= 1) v += __shfl_xor(v, o, 64);
    return v;
}

// tanh via single exp + hw rcp
__device__ __forceinline__ float tanh_fast(float x) {
    const float e = __expf(2.0f * x);
    return (e - 1.0f) * __builtin_amdgcn_rcpf(e + 1.0f);
}

__global__ void zero_tail_kernel(float* __restrict__ out) {
    out[4 * NB] = 0.0f;
    out[4 * NB + 1] = 0.0f;
}

__global__ __launch_bounds__(256, 4) void fwd_kernel(
    const int* __restrict__ user1, const int* __restrict__ item1,
    const int* __restrict__ user2, const int* __restrict__ item2,
    const int* __restrict__ u_his, const int* __restrict__ u_pos, const int* __restrict__ u_mask,
    const int* __restrict__ i_his, const int* __restrict__ i_pos, const int* __restrict__ i_mask,
    const float* __restrict__ user1_emb, const float* __restrict__ item1_emb,
    const float* __restrict__ user1_bias, const float* __restrict__ item1_bias,
    const float* __restrict__ u_pos_emb,
    const float* __restrict__ user2_emb, const float* __restrict__ item2_emb,
    const float* __restrict__ user2_bias, const float* __restrict__ item2_bias,
    const float* __restrict__ i_pos_emb,
    const float* __restrict__ attn_u_W, const float* __restrict__ attn_u_b,
    const float* __restrict__ attn_i_W, const float* __restrict__ attn_i_b,
    float* __restrict__ out)
{
    const int wave = threadIdx.x >> 6;
    const int d = threadIdx.x & 63;
    // force wave-uniform sample index into an SGPR so index/mask loads become s_load
    const int b = __builtin_amdgcn_readfirstlane(blockIdx.x * 4 + wave);

    const int iu1 = user1[b], ii1 = item1[b], iu2 = user2[b], ii2 = item2[b];

    // per-sample embedding rows (lane d holds element d)
    const float u1s = user1_emb[(long)iu1 * ND + d];
    const float i1s = item1_emb[(long)ii1 * ND + d];
    const float u1r = user2_emb[(long)iu1 * ND + d];
    const float i1r = item2_emb[(long)ii1 * ND + d];
    const float u2s = user2_emb[(long)iu2 * ND + d];
    const float i2s = item2_emb[(long)ii2 * ND + d];
    const float u2r = user1_emb[(long)iu2 * ND + d];
    const float i2r = item1_emb[(long)ii2 * ND + d];

    // attention weights: W[0:64] -> query (data), W[64:128] -> key
    const float Wku = attn_u_W[ND + d];
    const float Wki = attn_i_W[ND + d];
    const float bu = attn_u_b[0], bi = attn_i_b[0];

    // query-side score constants (wave-uniform after reduce)
    const float cq_us = wsum(i1s * attn_u_W[d]) + bu;  // u_ds query = i1s
    const float cq_ur = wsum(i1r * attn_u_W[d]) + bu;  // u_dr query = i1r
    const float cq_ir = wsum(u1r * attn_i_W[d]) + bi;  // i_dr query = u1r
    const float cq_is = wsum(u1s * attn_i_W[d]) + bi;  // i_ds query = u1s

    // masked-slot (k == 0) softmax terms: exp(tanh(cq + 0))
    const float e0_us = __expf(tanh_fast(cq_us));
    const float e0_ur = __expf(tanh_fast(cq_ur));
    const float e0_ir = __expf(tanh_fast(cq_ir));
    const float e0_is = __expf(tanh_fast(cq_is));

    // ===== U-history: streaming softmax (tanh-bounded => no max shift), skip masked =====
    float o_us = 0.0f, o_ur = 0.0f, den_us = 0.0f, den_ur = 0.0f, reg_u = 0.0f;
#pragma unroll 2
    for (int h = 0; h < NH; ++h) {
        if (u_mask[b * NH + h] != 0) {          // wave-uniform scalar branch
            const int ih = u_his[b * NH + h];
            const int ip = u_pos[b * NH + h];
            const float ku = item1_emb[(long)ih * ND + d];
            const float pu = u_pos_emb[ip * ND + d];
            const float k = ku + pu;            // mask==1 here
            reg_u += ku * ku;
            const float s = wsum(k * Wku);
            const float e_us = __expf(tanh_fast(cq_us + s));
            const float e_ur = __expf(tanh_fast(cq_ur + s));
            o_us += e_us * k;  den_us += e_us;
            o_ur += e_ur * k;  den_ur += e_ur;
        } else {
            den_us += e0_us;
            den_ur += e0_ur;
        }
    }
    o_us *= __builtin_amdgcn_rcpf(den_us);
    o_ur *= __builtin_amdgcn_rcpf(den_ur);

    // ===== I-history =====
    float o_ir = 0.0f, o_is = 0.0f, den_ir = 0.0f, den_is = 0.0f, reg_i = 0.0f;
#pragma unroll 2
    for (int h = 0; h < NH; ++h) {
        if (i_mask[b * NH + h] != 0) {
            const int ih = i_his[b * NH + h];
            const int ip = i_pos[b * NH + h];
            const float ki = user2_emb[(long)ih * ND + d];
            const float pi = i_pos_emb[ip * ND + d];
            const float k = ki + pi;
            reg_i += ki * ki;
            const float s = wsum(k * Wki);
            const float e_ir = __expf(tanh_fast(cq_ir + s));
            const float e_is = __expf(tanh_fast(cq_is + s));
            o_ir += e_ir * k;  den_ir += e_ir;
            o_is += e_is * k;  den_is += e_is;
        } else {
            den_ir += e0_ir;
            den_is += e0_is;
        }
    }
    o_ir *= __builtin_amdgcn_rcpf(den_ir);
    o_is *= __builtin_amdgcn_rcpf(den_is);

    // ===== logits + reg losses =====
    const float l_us = wsum((o_us + i1s) * u1s);
    const float l_ir = wsum((o_ir + i1r) * u1r);
    const float l_ur = wsum((o_ur + i2r) * u2r);
    const float l_is = wsum((o_is + i2s) * u2s);
    const float r1 = wsum(u1s * u1s + i1s * i1s + reg_u);
    const float r2 = wsum(u2s * u2s + i2s * i2s + reg_i);

    __shared__ float red[8];
    if (d == 0) {
        out[b]          = user1_bias[iu1] + item1_bias[ii1] + l_us;
        out[NB + b]     = user2_bias[iu1] + item2_bias[ii1] + l_ir;
        out[2 * NB + b] = user1_bias[iu2] + item1_bias[ii2] + l_ur;
        out[3 * NB + b] = user2_bias[iu2] + item2_bias[ii2] + l_is;
        red[wave] = r1;
        red[4 + wave] = r2;
    }
    __syncthreads();
    if (threadIdx.x == 0) {
        atomicAdd(&out[4 * NB],     red[0] + red[1] + red[2] + red[3]);
        atomicAdd(&out[4 * NB + 1], red[4] + red[5] + red[6] + red[7]);
    }
}

extern "C" void kernel_launch(void* const* d_in, const int* in_sizes, int n_in,
                              void* d_out, int out_size, void* d_ws, size_t ws_size,
                              hipStream_t stream) {
    const int* user1 = (const int*)d_in[0];
    const int* item1 = (const int*)d_in[1];
    const int* user2 = (const int*)d_in[2];
    const int* item2 = (const int*)d_in[3];
    const int* u_his = (const int*)d_in[4];
    const int* u_pos = (const int*)d_in[5];
    const int* u_msk = (const int*)d_in[6];
    const int* i_his = (const int*)d_in[7];
    const int* i_pos = (const int*)d_in[8];
    const int* i_msk = (const int*)d_in[9];
    const float* user1_emb  = (const float*)d_in[10];
    const float* item1_emb  = (const float*)d_in[11];
    const float* user1_bias = (const float*)d_in[12];
    const float* item1_bias = (const float*)d_in[13];
    const float* u_pos_emb  = (const float*)d_in[14];
    const float* user2_emb  = (const float*)d_in[15];
    const float* item2_emb  = (const float*)d_in[16];
    const float* user2_bias = (const float*)d_in[17];
    const float* item2_bias = (const float*)d_in[18];
    const float* i_pos_emb  = (const float*)d_in[19];
    const float* attn_u_W = (const float*)d_in[20];
    const float* attn_u_b = (const float*)d_in[21];
    const float* attn_i_W = (const float*)d_in[22];
    const float* attn_i_b = (const float*)d_in[23];
    float* out = (float*)d_out;

    zero_tail_kernel<<<1, 1, 0, stream>>>(out);
    fwd_kernel<<<NB / 4, 256, 0, stream>>>(
        user1, item1, user2, item2,
        u_his, u_pos, u_msk, i_his, i_pos, i_msk,
        user1_emb, item1_emb, user1_bias, item1_bias, u_pos_emb,
        user2_emb, item2_emb, user2_bias, item2_bias, i_pos_emb,
        attn_u_W, attn_u_b, attn_i_W, attn_i_b,
        out);
}

// Round 4
// 219.220 us; speedup vs baseline: 2.6008x; 1.2054x over previous
//
#include <hip/hip_runtime.h>

#define NB 8192
#define NH 50
#define ND 64

__device__ __forceinline__ float wsum(float v) {
#pragma unroll
    for (int o = 32; o > 0; o >>= 1) v += __shfl_xor(v, o, 64);
    return v;
}

__device__ __forceinline__ float tanh_fast(float x) {
    const float e = __expf(2.0f * x);
    return (e - 1.0f) * __builtin_amdgcn_rcpf(e + 1.0f);
}

// fwd: one wave per (sample, history-side). wave&1==0 -> U-history, ==1 -> I-history.
// Block = 256 threads = 2 samples. The two sides are fully independent through the
// logits, so no LDS / syncthreads at all.
__global__ __launch_bounds__(256, 8) void fwd_kernel(
    const int* __restrict__ user1, const int* __restrict__ item1,
    const int* __restrict__ user2, const int* __restrict__ item2,
    const int* __restrict__ u_his, const int* __restrict__ u_pos, const int* __restrict__ u_mask,
    const int* __restrict__ i_his, const int* __restrict__ i_pos, const int* __restrict__ i_mask,
    const float* __restrict__ user1_emb, const float* __restrict__ item1_emb,
    const float* __restrict__ user1_bias, const float* __restrict__ item1_bias,
    const float* __restrict__ u_pos_emb,
    const float* __restrict__ user2_emb, const float* __restrict__ item2_emb,
    const float* __restrict__ user2_bias, const float* __restrict__ item2_bias,
    const float* __restrict__ i_pos_emb,
    const float* __restrict__ attn_u_W, const float* __restrict__ attn_u_b,
    const float* __restrict__ attn_i_W, const float* __restrict__ attn_i_b,
    float* __restrict__ out, float* __restrict__ ws)
{
    const int wave = threadIdx.x >> 6;
    const int d = threadIdx.x & 63;
    const int b = __builtin_amdgcn_readfirstlane(blockIdx.x * 2 + (wave >> 1));
    const bool iw = (wave & 1);  // wave-uniform role: false=U, true=I

    const int iu1 = user1[b], ii1 = item1[b], iu2 = user2[b], ii2 = item2[b];

    // role-selected tables (all wave-uniform selects)
    const int*   his  = iw ? i_his  : u_his;
    const int*   posa = iw ? i_pos  : u_pos;
    const int*   msk  = iw ? i_mask : u_mask;
    const float* ktab = iw ? user2_emb : item1_emb;   // history-key table
    const float* ptab = iw ? i_pos_emb : u_pos_emb;
    const float* W    = iw ? attn_i_W  : attn_u_W;
    const float  bb   = iw ? attn_i_b[0] : attn_u_b[0];

    // queries: U: qa=i1s (item1_emb[ii1]), qb=i1r (item2_emb[ii1])
    //          I: qa=u1r (user2_emb[iu1]), qb=u1s (user1_emb[iu1])
    const float* qa_tab = iw ? user2_emb : item1_emb;
    const float* qb_tab = iw ? user1_emb : item2_emb;
    const int    qidx   = iw ? iu1 : ii1;
    const float qa = qa_tab[(size_t)qidx * ND + d];
    const float qb = qb_tab[(size_t)qidx * ND + d];
    const float Wq = W[d], Wk = W[ND + d];
    const float cq_a = wsum(qa * Wq) + bb;
    const float cq_b = wsum(qb * Wq) + bb;

    // ---- lane-parallel slot load + ballot compaction (branchless main loop) ----
    int hidx = 0, hpos = 0;
    bool act = false;
    if (d < NH) {
        hidx = his[b * NH + d];
        hpos = posa[b * NH + d];
        act  = (msk[b * NH + d] != 0);
    }
    const unsigned long long bal = __ballot(act);
    const int nact = __builtin_amdgcn_readfirstlane(__popcll(bal));
    const int below = __builtin_amdgcn_mbcnt_hi(
        (unsigned)(bal >> 32), __builtin_amdgcn_mbcnt_lo((unsigned)bal, 0));
    const int tgt = (act ? below : 63) << 2;
    const int idx_c = __builtin_amdgcn_ds_permute(tgt, hidx);
    const int pos_c = __builtin_amdgcn_ds_permute(tgt, hpos);

    // ---- streaming softmax over active slots only (tanh-bounded => no max shift) ----
    float o_a = 0.0f, o_b = 0.0f, den_a = 0.0f, den_b = 0.0f, reg = 0.0f;
#pragma unroll 4
    for (int h = 0; h < nact; ++h) {
        const int ih = __builtin_amdgcn_readlane(idx_c, h);  // SGPR row index -> saddr gather
        const int ip = __builtin_amdgcn_readlane(pos_c, h);
        const float kv = ktab[(size_t)ih * ND + d];
        const float pv = ptab[(size_t)ip * ND + d];
        const float k = kv + pv;
        reg += kv * kv;
        const float s = wsum(k * Wk);
        const float ea = __expf(tanh_fast(cq_a + s));
        const float eb = __expf(tanh_fast(cq_b + s));
        o_a += ea * k;  den_a += ea;
        o_b += eb * k;  den_b += eb;
    }
    // masked slots: key==0 -> weight exp(tanh(cq)), zero o/reg contribution
    den_a += (float)(NH - nact) * __expf(tanh_fast(cq_a));
    den_b += (float)(NH - nact) * __expf(tanh_fast(cq_b));
    o_a *= __builtin_amdgcn_rcpf(den_a);
    o_b *= __builtin_amdgcn_rcpf(den_b);

    // ---- epilogue: this wave's two logits + its reg-loss partial ----
    // la: U: (o_us + i1s)*u1s   [add=qa,  mul=user1_emb[iu1]]
    //     I: (o_ir + i1r)*u1r   [add=item2_emb[ii1], mul=qa]
    const float pa = iw ? item2_emb[(size_t)ii1 * ND + d] : user1_emb[(size_t)iu1 * ND + d];
    const float add_a = iw ? pa : qa;
    const float mul_a = iw ? qa : pa;
    // lb: U: (o_ur + i2r)*u2r   I: (o_is + i2s)*u2s
    const float add_b = (iw ? item2_emb : item1_emb)[(size_t)ii2 * ND + d];
    const float mul_b = (iw ? user2_emb : user1_emb)[(size_t)iu2 * ND + d];

    const float l_a = wsum((o_a + add_a) * mul_a);
    const float l_b = wsum((o_b + add_b) * mul_b);
    // r1 = u1s^2 + i1s^2 + sum(u_hiss^2)   (U-wave: mul_a=u1s, qa=i1s)
    // r2 = u2s^2 + i2s^2 + sum(i_hiss^2)   (I-wave: mul_b=u2s, add_b=i2s)
    const float rv = iw ? (mul_b * mul_b + add_b * add_b) : (mul_a * mul_a + qa * qa);
    const float r = wsum(rv + reg);

    const float* ub = iw ? user2_bias : user1_bias;
    const float* ib = iw ? item2_bias : item1_bias;
    if (d == 0) {
        out[(iw ? NB : 0) + b]          = ub[iu1] + ib[ii1] + l_a;
        out[(iw ? 3 * NB : 2 * NB) + b] = ub[iu2] + ib[ii2] + l_b;
        ws[(iw ? NB : 0) + b] = r;
    }
}

__global__ void reduce_kernel(const float* __restrict__ ws, float* __restrict__ out) {
    float a = 0.0f, c = 0.0f;
    for (int i = threadIdx.x; i < NB; i += 256) {
        a += ws[i];
        c += ws[NB + i];
    }
    a = wsum(a);
    c = wsum(c);
    __shared__ float sa[4], sc[4];
    const int w = threadIdx.x >> 6, d = threadIdx.x & 63;
    if (d == 0) { sa[w] = a; sc[w] = c; }
    __syncthreads();
    if (threadIdx.x == 0) {
        out[4 * NB]     = sa[0] + sa[1] + sa[2] + sa[3];
        out[4 * NB + 1] = sc[0] + sc[1] + sc[2] + sc[3];
    }
}

extern "C" void kernel_launch(void* const* d_in, const int* in_sizes, int n_in,
                              void* d_out, int out_size, void* d_ws, size_t ws_size,
                              hipStream_t stream) {
    const int* user1 = (const int*)d_in[0];
    const int* item1 = (const int*)d_in[1];
    const int* user2 = (const int*)d_in[2];
    const int* item2 = (const int*)d_in[3];
    const int* u_his = (const int*)d_in[4];
    const int* u_pos = (const int*)d_in[5];
    const int* u_msk = (const int*)d_in[6];
    const int* i_his = (const int*)d_in[7];
    const int* i_pos = (const int*)d_in[8];
    const int* i_msk = (const int*)d_in[9];
    const float* user1_emb  = (const float*)d_in[10];
    const float* item1_emb  = (const float*)d_in[11];
    const float* user1_bias = (const float*)d_in[12];
    const float* item1_bias = (const float*)d_in[13];
    const float* u_pos_emb  = (const float*)d_in[14];
    const float* user2_emb  = (const float*)d_in[15];
    const float* item2_emb  = (const float*)d_in[16];
    const float* user2_bias = (const float*)d_in[17];
    const float* item2_bias = (const float*)d_in[18];
    const float* i_pos_emb  = (const float*)d_in[19];
    const float* attn_u_W = (const float*)d_in[20];
    const float* attn_u_b = (const float*)d_in[21];
    const float* attn_i_W = (const float*)d_in[22];
    const float* attn_i_b = (const float*)d_in[23];
    float* out = (float*)d_out;
    float* ws  = (float*)d_ws;

    fwd_kernel<<<NB / 2, 256, 0, stream>>>(
        user1, item1, user2, item2,
        u_his, u_pos, u_msk, i_his, i_pos, i_msk,
        user1_emb, item1_emb, user1_bias, item1_bias, u_pos_emb,
        user2_emb, item2_emb, user2_bias, item2_bias, i_pos_emb,
        attn_u_W, attn_u_b, attn_i_W, attn_i_b,
        out, ws);
    reduce_kernel<<<1, 256, 0, stream>>>(ws, out);
}

// Round 5
// 207.847 us; speedup vs baseline: 2.7431x; 1.0547x over previous
//
#include <hip/hip_runtime.h>

#define NB 8192
#define NH 50
#define ND 64

__device__ __forceinline__ float wsum(float v) {
#pragma unroll
    for (int o = 32; o > 0; o >>= 1) v += __shfl_xor(v, o, 64);
    return v;
}

__device__ __forceinline__ float tanh_fast(float x) {
    const float e = __expf(2.0f * x);
    return (e - 1.0f) * __builtin_amdgcn_rcpf(e + 1.0f);
}

// ---------------- precompute: KW[row] = dot(table[row], Wkey) ----------------
// 4 jobs in one launch; 4 rows per wave (16-lane groups, float4 loads).
__global__ __launch_bounds__(256, 8) void kw_kernel(
    const float* __restrict__ t0, const float* __restrict__ t1,
    const float* __restrict__ t2, const float* __restrict__ t3,
    const float* __restrict__ w0, const float* __restrict__ w1,
    const float* __restrict__ w2, const float* __restrict__ w3,
    float* __restrict__ o0, float* __restrict__ o1,
    float* __restrict__ o2, float* __restrict__ o3,
    int r0, int r1, int r2, int r3,
    int b1, int b2, int b3)
{
    const int blk = blockIdx.x;
    const float* tab; const float* W; float* o; int rows, base;
    if (blk < b1)      { tab = t0; W = w0; o = o0; rows = r0; base = blk; }
    else if (blk < b2) { tab = t1; W = w1; o = o1; rows = r1; base = blk - b1; }
    else if (blk < b3) { tab = t2; W = w2; o = o2; rows = r2; base = blk - b2; }
    else               { tab = t3; W = w3; o = o3; rows = r3; base = blk - b3; }
    const int lane = threadIdx.x & 63;
    const int wv = threadIdx.x >> 6;
    const int sub = lane >> 4, j = lane & 15;
    const int row = base * 16 + wv * 4 + sub;
    const int rowc = min(row, rows - 1);
    const float4 v = *(const float4*)(tab + (size_t)rowc * ND + j * 4);
    const float4 w = *(const float4*)(W + j * 4);
    float p = v.x * w.x + v.y * w.y + v.z * w.z + v.w * w.w;
    p += __shfl_xor(p, 1, 64);
    p += __shfl_xor(p, 2, 64);
    p += __shfl_xor(p, 4, 64);
    p += __shfl_xor(p, 8, 64);
    if (j == 0 && row < rows) o[row] = p;
}

// ---------------- fwd: one wave per (sample, side); scores via KW/PW gathers ----------------
__global__ __launch_bounds__(256, 8) void fwd_kernel(
    const int* __restrict__ user1, const int* __restrict__ item1,
    const int* __restrict__ user2, const int* __restrict__ item2,
    const int* __restrict__ u_his, const int* __restrict__ u_pos, const int* __restrict__ u_mask,
    const int* __restrict__ i_his, const int* __restrict__ i_pos, const int* __restrict__ i_mask,
    const float* __restrict__ user1_emb, const float* __restrict__ item1_emb,
    const float* __restrict__ user1_bias, const float* __restrict__ item1_bias,
    const float* __restrict__ u_pos_emb,
    const float* __restrict__ user2_emb, const float* __restrict__ item2_emb,
    const float* __restrict__ user2_bias, const float* __restrict__ item2_bias,
    const float* __restrict__ i_pos_emb,
    const float* __restrict__ attn_u_W, const float* __restrict__ attn_u_b,
    const float* __restrict__ attn_i_W, const float* __restrict__ attn_i_b,
    const float* __restrict__ KWu, const float* __restrict__ KWi,
    const float* __restrict__ PWu, const float* __restrict__ PWi,
    float* __restrict__ out, float* __restrict__ ws)
{
    const int wave = threadIdx.x >> 6;
    const int d = threadIdx.x & 63;
    const int b = __builtin_amdgcn_readfirstlane(blockIdx.x * 2 + (wave >> 1));
    const bool iw = (wave & 1);  // wave-uniform: false=U-side, true=I-side

    const int iu1 = user1[b], ii1 = item1[b], iu2 = user2[b], ii2 = item2[b];

    const int*   his  = iw ? i_his  : u_his;
    const int*   posa = iw ? i_pos  : u_pos;
    const int*   msk  = iw ? i_mask : u_mask;
    const float* ktab = iw ? user2_emb : item1_emb;
    const float* ptab = iw ? i_pos_emb : u_pos_emb;
    const float* W    = iw ? attn_i_W  : attn_u_W;
    const float  bb   = iw ? attn_i_b[0] : attn_u_b[0];
    const float* KW   = iw ? KWi : KWu;
    const float* PW   = iw ? PWi : PWu;

    const float* qa_tab = iw ? user2_emb : item1_emb;
    const float* qb_tab = iw ? user1_emb : item2_emb;
    const int    qidx   = iw ? iu1 : ii1;
    const float qa = qa_tab[(size_t)qidx * ND + d];
    const float qb = qb_tab[(size_t)qidx * ND + d];
    const float Wq = W[d];
    const float cq_a = wsum(qa * Wq) + bb;
    const float cq_b = wsum(qb * Wq) + bb;
    const float e0_a = __expf(tanh_fast(cq_a));
    const float e0_b = __expf(tanh_fast(cq_b));

    // lane-parallel slot metadata + scores (lane h owns slot h)
    int hidx = 0, hpos = 0;
    bool act = false;
    if (d < NH) {
        hidx = his[b * NH + d];
        hpos = posa[b * NH + d];
        act  = (msk[b * NH + d] != 0);
    }
    const float s = KW[hidx] + PW[hpos];
    float e_a = 0.0f, e_b = 0.0f;
    if (d < NH) {
        e_a = act ? __expf(tanh_fast(cq_a + s)) : e0_a;
        e_b = act ? __expf(tanh_fast(cq_b + s)) : e0_b;
    }
    const float den_a = wsum(e_a);
    const float den_b = wsum(e_b);

    // ballot compaction of active slots
    const unsigned long long bal = __ballot(act);
    const int nact = __builtin_amdgcn_readfirstlane(__popcll(bal));
    const int below = __builtin_amdgcn_mbcnt_hi(
        (unsigned)(bal >> 32), __builtin_amdgcn_mbcnt_lo((unsigned)bal, 0));
    const int tgt = (act ? below : 63) << 2;
    const int idx_c = __builtin_amdgcn_ds_permute(tgt, hidx);
    const int pos_c = __builtin_amdgcn_ds_permute(tgt, hpos);
    const int ea_c  = __builtin_amdgcn_ds_permute(tgt, __float_as_int(e_a));
    const int eb_c  = __builtin_amdgcn_ds_permute(tgt, __float_as_int(e_b));

    // pure gather+FMA loop: no cross-lane ops, iterations independent
    float o_a = 0.0f, o_b = 0.0f, reg = 0.0f;
#pragma unroll 4
    for (int h = 0; h < nact; ++h) {
        const int ih = __builtin_amdgcn_readlane(idx_c, h);
        const int ip = __builtin_amdgcn_readlane(pos_c, h);
        const float ea = __int_as_float(__builtin_amdgcn_readlane(ea_c, h));
        const float eb = __int_as_float(__builtin_amdgcn_readlane(eb_c, h));
        const float kv = ktab[(size_t)ih * ND + d];
        const float pv = ptab[ip * ND + d];
        const float k = kv + pv;
        o_a += ea * k;
        o_b += eb * k;
        reg += kv * kv;
    }
    o_a *= __builtin_amdgcn_rcpf(den_a);
    o_b *= __builtin_amdgcn_rcpf(den_b);

    // epilogue (identical to round 4)
    const float pa = iw ? item2_emb[(size_t)ii1 * ND + d] : user1_emb[(size_t)iu1 * ND + d];
    const float add_a = iw ? pa : qa;
    const float mul_a = iw ? qa : pa;
    const float add_b = (iw ? item2_emb : item1_emb)[(size_t)ii2 * ND + d];
    const float mul_b = (iw ? user2_emb : user1_emb)[(size_t)iu2 * ND + d];

    const float l_a = wsum((o_a + add_a) * mul_a);
    const float l_b = wsum((o_b + add_b) * mul_b);
    const float rv = iw ? (mul_b * mul_b + add_b * add_b) : (mul_a * mul_a + qa * qa);
    const float r = wsum(rv + reg);

    const float* ub = iw ? user2_bias : user1_bias;
    const float* ib = iw ? item2_bias : item1_bias;
    if (d == 0) {
        out[(iw ? NB : 0) + b]          = ub[iu1] + ib[ii1] + l_a;
        out[(iw ? 3 * NB : 2 * NB) + b] = ub[iu2] + ib[ii2] + l_b;
        ws[(iw ? NB : 0) + b] = r;
    }
}

// ---------------- fallback (round-4 kernel): used only if ws too small ----------------
__global__ __launch_bounds__(256, 8) void fwd_fallback(
    const int* __restrict__ user1, const int* __restrict__ item1,
    const int* __restrict__ user2, const int* __restrict__ item2,
    const int* __restrict__ u_his, const int* __restrict__ u_pos, const int* __restrict__ u_mask,
    const int* __restrict__ i_his, const int* __restrict__ i_pos, const int* __restrict__ i_mask,
    const float* __restrict__ user1_emb, const float* __restrict__ item1_emb,
    const float* __restrict__ user1_bias, const float* __restrict__ item1_bias,
    const float* __restrict__ u_pos_emb,
    const float* __restrict__ user2_emb, const float* __restrict__ item2_emb,
    const float* __restrict__ user2_bias, const float* __restrict__ item2_bias,
    const float* __restrict__ i_pos_emb,
    const float* __restrict__ attn_u_W, const float* __restrict__ attn_u_b,
    const float* __restrict__ attn_i_W, const float* __restrict__ attn_i_b,
    float* __restrict__ out, float* __restrict__ ws)
{
    const int wave = threadIdx.x >> 6;
    const int d = threadIdx.x & 63;
    const int b = __builtin_amdgcn_readfirstlane(blockIdx.x * 2 + (wave >> 1));
    const bool iw = (wave & 1);

    const int iu1 = user1[b], ii1 = item1[b], iu2 = user2[b], ii2 = item2[b];
    const int*   his  = iw ? i_his  : u_his;
    const int*   posa = iw ? i_pos  : u_pos;
    const int*   msk  = iw ? i_mask : u_mask;
    const float* ktab = iw ? user2_emb : item1_emb;
    const float* ptab = iw ? i_pos_emb : u_pos_emb;
    const float* W    = iw ? attn_i_W  : attn_u_W;
    const float  bb   = iw ? attn_i_b[0] : attn_u_b[0];
    const float* qa_tab = iw ? user2_emb : item1_emb;
    const float* qb_tab = iw ? user1_emb : item2_emb;
    const int    qidx   = iw ? iu1 : ii1;
    const float qa = qa_tab[(size_t)qidx * ND + d];
    const float qb = qb_tab[(size_t)qidx * ND + d];
    const float Wq = W[d], Wk = W[ND + d];
    const float cq_a = wsum(qa * Wq) + bb;
    const float cq_b = wsum(qb * Wq) + bb;

    int hidx = 0, hpos = 0;
    bool act = false;
    if (d < NH) {
        hidx = his[b * NH + d];
        hpos = posa[b * NH + d];
        act  = (msk[b * NH + d] != 0);
    }
    const unsigned long long bal = __ballot(act);
    const int nact = __builtin_amdgcn_readfirstlane(__popcll(bal));
    const int below = __builtin_amdgcn_mbcnt_hi(
        (unsigned)(bal >> 32), __builtin_amdgcn_mbcnt_lo((unsigned)bal, 0));
    const int tgt = (act ? below : 63) << 2;
    const int idx_c = __builtin_amdgcn_ds_permute(tgt, hidx);
    const int pos_c = __builtin_amdgcn_ds_permute(tgt, hpos);

    float o_a = 0.0f, o_b = 0.0f, den_a = 0.0f, den_b = 0.0f, reg = 0.0f;
#pragma unroll 4
    for (int h = 0; h < nact; ++h) {
        const int ih = __builtin_amdgcn_readlane(idx_c, h);
        const int ip = __builtin_amdgcn_readlane(pos_c, h);
        const float kv = ktab[(size_t)ih * ND + d];
        const float pv = ptab[(size_t)ip * ND + d];
        const float k = kv + pv;
        reg += kv * kv;
        const float s = wsum(k * Wk);
        const float ea = __expf(tanh_fast(cq_a + s));
        const float eb = __expf(tanh_fast(cq_b + s));
        o_a += ea * k;  den_a += ea;
        o_b += eb * k;  den_b += eb;
    }
    den_a += (float)(NH - nact) * __expf(tanh_fast(cq_a));
    den_b += (float)(NH - nact) * __expf(tanh_fast(cq_b));
    o_a *= __builtin_amdgcn_rcpf(den_a);
    o_b *= __builtin_amdgcn_rcpf(den_b);

    const float pa = iw ? item2_emb[(size_t)ii1 * ND + d] : user1_emb[(size_t)iu1 * ND + d];
    const float add_a = iw ? pa : qa;
    const float mul_a = iw ? qa : pa;
    const float add_b = (iw ? item2_emb : item1_emb)[(size_t)ii2 * ND + d];
    const float mul_b = (iw ? user2_emb : user1_emb)[(size_t)iu2 * ND + d];
    const float l_a = wsum((o_a + add_a) * mul_a);
    const float l_b = wsum((o_b + add_b) * mul_b);
    const float rv = iw ? (mul_b * mul_b + add_b * add_b) : (mul_a * mul_a + qa * qa);
    const float r = wsum(rv + reg);
    const float* ub = iw ? user2_bias : user1_bias;
    const float* ib = iw ? item2_bias : item1_bias;
    if (d == 0) {
        out[(iw ? NB : 0) + b]          = ub[iu1] + ib[ii1] + l_a;
        out[(iw ? 3 * NB : 2 * NB) + b] = ub[iu2] + ib[ii2] + l_b;
        ws[(iw ? NB : 0) + b] = r;
    }
}

__global__ void reduce_kernel(const float* __restrict__ ws, float* __restrict__ out) {
    float a = 0.0f, c = 0.0f;
    for (int i = threadIdx.x; i < NB; i += 256) {
        a += ws[i];
        c += ws[NB + i];
    }
    a = wsum(a);
    c = wsum(c);
    __shared__ float sa[4], sc[4];
    const int w = threadIdx.x >> 6, d = threadIdx.x & 63;
    if (d == 0) { sa[w] = a; sc[w] = c; }
    __syncthreads();
    if (threadIdx.x == 0) {
        out[4 * NB]     = sa[0] + sa[1] + sa[2] + sa[3];
        out[4 * NB + 1] = sc[0] + sc[1] + sc[2] + sc[3];
    }
}

extern "C" void kernel_launch(void* const* d_in, const int* in_sizes, int n_in,
                              void* d_out, int out_size, void* d_ws, size_t ws_size,
                              hipStream_t stream) {
    const int* user1 = (const int*)d_in[0];
    const int* item1 = (const int*)d_in[1];
    const int* user2 = (const int*)d_in[2];
    const int* item2 = (const int*)d_in[3];
    const int* u_his = (const int*)d_in[4];
    const int* u_pos = (const int*)d_in[5];
    const int* u_msk = (const int*)d_in[6];
    const int* i_his = (const int*)d_in[7];
    const int* i_pos = (const int*)d_in[8];
    const int* i_msk = (const int*)d_in[9];
    const float* user1_emb  = (const float*)d_in[10];
    const float* item1_emb  = (const float*)d_in[11];
    const float* user1_bias = (const float*)d_in[12];
    const float* item1_bias = (const float*)d_in[13];
    const float* u_pos_emb  = (const float*)d_in[14];
    const float* user2_emb  = (const float*)d_in[15];
    const float* item2_emb  = (const float*)d_in[16];
    const float* user2_bias = (const float*)d_in[17];
    const float* item2_bias = (const float*)d_in[18];
    const float* i_pos_emb  = (const float*)d_in[19];
    const float* attn_u_W = (const float*)d_in[20];
    const float* attn_u_b = (const float*)d_in[21];
    const float* attn_i_W = (const float*)d_in[22];
    const float* attn_i_b = (const float*)d_in[23];
    float* out = (float*)d_out;
    float* ws  = (float*)d_ws;

    const int I_rows = in_sizes[11] / ND;  // item1_emb rows
    const int U_rows = in_sizes[15] / ND;  // user2_emb rows
    const int P_rows = in_sizes[14] / ND;  // pos table rows

    float* KWu = ws + 2 * NB;
    float* KWi = KWu + I_rows;
    float* PWu = KWi + U_rows;
    float* PWi = PWu + 64;
    const size_t need = (size_t)(2 * NB + I_rows + U_rows + 128) * sizeof(float);

    if (ws_size >= need) {
        const int nb0 = (I_rows + 15) / 16;
        const int nb1 = (U_rows + 15) / 16;
        const int nb2 = (P_rows + 15) / 16;
        const int b1 = nb0, b2 = nb0 + nb1, b3 = nb0 + nb1 + nb2;
        const int total = b3 + nb2;
        kw_kernel<<<total, 256, 0, stream>>>(
            item1_emb, user2_emb, u_pos_emb, i_pos_emb,
            attn_u_W + ND, attn_i_W + ND, attn_u_W + ND, attn_i_W + ND,
            KWu, KWi, PWu, PWi,
            I_rows, U_rows, P_rows, P_rows,
            b1, b2, b3);
        fwd_kernel<<<NB / 2, 256, 0, stream>>>(
            user1, item1, user2, item2,
            u_his, u_pos, u_msk, i_his, i_pos, i_msk,
            user1_emb, item1_emb, user1_bias, item1_bias, u_pos_emb,
            user2_emb, item2_emb, user2_bias, item2_bias, i_pos_emb,
            attn_u_W, attn_u_b, attn_i_W, attn_i_b,
            KWu, KWi, PWu, PWi,
            out, ws);
    } else {
        fwd_fallback<<<NB / 2, 256, 0, stream>>>(
            user1, item1, user2, item2,
            u_his, u_pos, u_msk, i_his, i_pos, i_msk,
            user1_emb, item1_emb, user1_bias, item1_bias, u_pos_emb,
            user2_emb, item2_emb, user2_bias, item2_bias, i_pos_emb,
            attn_u_W, attn_u_b, attn_i_W, attn_i_b,
            out, ws);
    }
    reduce_kernel<<<1, 256, 0, stream>>>(ws, out);
}